// Round 2
// 895.709 us; speedup vs baseline: 1.0415x; 1.0415x over previous
//
#include <hip/hip_runtime.h>
#include <math.h>

// Problem constants (from reference):
//   N = 500000 nodes, C = 256 channels, B = 1024 segments, hidden = C/R = 64
#define CCH   256
#define CCH4  64        // C / 4 (float4 groups per row)
#define BSEG  1024
#define HID   64

typedef float v4 __attribute__((ext_vector_type(4)));

// ---------------------------------------------------------------------------
// Kernel 1 (fused): segment sum+max reduction AND the per-segment MLP.
// batch is sorted, so segment `seg` occupies a contiguous row range
// [start, end) found by binary search. One block per segment, 4 waves; each
// wave processes rows strided by 4 (unrolled x2 -> two 1KB loads in flight),
// with 64 lanes covering the 256 channels as float4.
// After the cross-wave reduce, the SAME block computes
//   y = relu( relu(sum@w1)@w2 + relu(max@w1)@w2 )
//     = relu( (hsum + hmax) @ w2 )          (second linear has no bias)
// directly from LDS, eliminating the old mlp_kernel launch and the
// sum_res/max_res global round-trip.
// ---------------------------------------------------------------------------
__global__ __launch_bounds__(256, 4) void seg_reduce_mlp_kernel(
    const float* __restrict__ x, const int* __restrict__ batch, int N,
    const float* __restrict__ w1, const float* __restrict__ w2,
    float* __restrict__ y) {
  int seg = blockIdx.x;
  __shared__ int s_bounds[2];
  if (threadIdx.x < 2) {
    int tgt = seg + (int)threadIdx.x;  // lower_bound(batch, tgt)
    int lo = 0, hi = N;
    while (lo < hi) {
      int mid = (lo + hi) >> 1;
      if (batch[mid] < tgt) lo = mid + 1; else hi = mid;
    }
    s_bounds[threadIdx.x] = lo;
  }
  __syncthreads();
  int start = s_bounds[0], end = s_bounds[1];

  int wave = threadIdx.x >> 6;
  int lane = threadIdx.x & 63;
  const float4* x4 = (const float4*)x;

  float4 s = make_float4(0.f, 0.f, 0.f, 0.f);
  float4 m = make_float4(-INFINITY, -INFINITY, -INFINITY, -INFINITY);
  // wave w owns rows start+w, start+w+4, start+w+8, ... ; unroll by 2 so two
  // independent 1KB row loads are outstanding per wave per iteration.
  int r = start + wave;
  for (; r + 4 < end; r += 8) {
    float4 v0 = x4[(size_t)r * CCH4 + lane];
    float4 v1 = x4[(size_t)(r + 4) * CCH4 + lane];
    s.x += v0.x; s.y += v0.y; s.z += v0.z; s.w += v0.w;
    m.x = fmaxf(m.x, v0.x); m.y = fmaxf(m.y, v0.y);
    m.z = fmaxf(m.z, v0.z); m.w = fmaxf(m.w, v0.w);
    s.x += v1.x; s.y += v1.y; s.z += v1.z; s.w += v1.w;
    m.x = fmaxf(m.x, v1.x); m.y = fmaxf(m.y, v1.y);
    m.z = fmaxf(m.z, v1.z); m.w = fmaxf(m.w, v1.w);
  }
  if (r < end) {
    float4 v = x4[(size_t)r * CCH4 + lane];
    s.x += v.x; s.y += v.y; s.z += v.z; s.w += v.w;
    m.x = fmaxf(m.x, v.x); m.y = fmaxf(m.y, v.y);
    m.z = fmaxf(m.z, v.z); m.w = fmaxf(m.w, v.w);
  }

  __shared__ float4 sh_s[4][CCH4];
  __shared__ float4 sh_m[4][CCH4];
  __shared__ float srow[CCH];
  __shared__ float mrow[CCH];
  __shared__ float hsum[HID];
  __shared__ float hmax[HID];

  sh_s[wave][lane] = s;
  sh_m[wave][lane] = m;
  __syncthreads();

  if (wave == 0) {
    float4 ts = sh_s[0][lane];
    float4 tm = sh_m[0][lane];
    for (int w = 1; w < 4; ++w) {
      float4 os = sh_s[w][lane];
      float4 om = sh_m[w][lane];
      ts.x += os.x; ts.y += os.y; ts.z += os.z; ts.w += os.w;
      tm.x = fmaxf(tm.x, om.x); tm.y = fmaxf(tm.y, om.y);
      tm.z = fmaxf(tm.z, om.z); tm.w = fmaxf(tm.w, om.w);
    }
    if (start == end) tm = make_float4(0.f, 0.f, 0.f, 0.f);  // empty segment
    ((float4*)srow)[lane] = ts;
    ((float4*)mrow)[lane] = tm;
  }
  __syncthreads();

  // Hidden layer: threads 0..63 -> hsum, 64..127 -> hmax. w1 reads are
  // coalesced (t consecutive over the minor dim) and L2-resident (64KB,
  // reused by all 1024 blocks).
  int t = threadIdx.x;
  if (t < HID) {
    float acc = 0.f;
    #pragma unroll 8
    for (int k = 0; k < CCH; ++k) acc = fmaf(srow[k], w1[k * HID + t], acc);
    hsum[t] = fmaxf(acc, 0.f);
  } else if (t < 2 * HID) {
    int j = t - HID;
    float acc = 0.f;
    #pragma unroll 8
    for (int k = 0; k < CCH; ++k) acc = fmaf(mrow[k], w1[k * HID + j], acc);
    hmax[j] = fmaxf(acc, 0.f);
  }
  __syncthreads();

  float acc = 0.f;
  #pragma unroll 8
  for (int j = 0; j < HID; ++j) acc = fmaf(hsum[j] + hmax[j], w2[j * CCH + t], acc);
  y[(size_t)seg * CCH + t] = fmaxf(acc, 0.f);
}

// ---------------------------------------------------------------------------
// Kernel 2: out[n][c] = x[n][c] * y[batch[n]][c], vectorized float4.
// All 64 lanes of a wave share node n -> batch[n] is one broadcast load; y is
// 1 MB (L2-resident) read as coalesced 1KB rows.
// Non-temporal x loads + out stores: x is dead after this kernel and out is
// never re-read, so neither should allocate/promote in L2/L3 -- this
// preserves the x-tail lines the reduce pass left in the 256MB L3 (nt loads
// still HIT resident lines; they just don't pollute on miss).
// ---------------------------------------------------------------------------
__global__ __launch_bounds__(256) void gate_kernel(
    const float* __restrict__ x, const int* __restrict__ batch,
    const float* __restrict__ y, float* __restrict__ out, int total4) {
  int idx = blockIdx.x * blockDim.x + threadIdx.x;
  if (idx >= total4) return;
  int n = idx >> 6;        // node
  int q = idx & 63;        // float4 group within row
  int b = batch[n];
  const v4* x4 = (const v4*)x;
  const v4* y4 = (const v4*)y;
  v4 xv = __builtin_nontemporal_load(&x4[idx]);
  v4 yv = y4[(size_t)b * CCH4 + q];
  v4 o = xv * yv;
  __builtin_nontemporal_store(o, (v4*)out + idx);
}

extern "C" void kernel_launch(void* const* d_in, const int* in_sizes, int n_in,
                              void* d_out, int out_size, void* d_ws, size_t ws_size,
                              hipStream_t stream) {
  const float* x     = (const float*)d_in[0];   // [N, C]
  const int*   batch = (const int*)d_in[1];     // [N]
  const float* w1    = (const float*)d_in[2];   // [C, 64]
  const float* w2    = (const float*)d_in[3];   // [64, C]
  float* out = (float*)d_out;                   // [N, C]

  int N = in_sizes[1];                          // 500000

  // Workspace layout: y [B*C]  (1 MB)
  float* y = (float*)d_ws;

  seg_reduce_mlp_kernel<<<BSEG, 256, 0, stream>>>(x, batch, N, w1, w2, y);

  int total4 = N * CCH4;                        // N*C/4 = 32,000,000
  int blocks = (total4 + 255) / 256;
  gate_kernel<<<blocks, 256, 0, stream>>>(x, batch, y, out, total4);
}